// Round 1
// baseline (699.100 us; speedup 1.0000x reference)
//
#include <hip/hip_runtime.h>

#define NBATCH 32
#define NN     1024     // d_model = number of nodes
#define NF     128      // win_size = node feature dim
#define NDG    64       // graph embed dim
#define TOPK   15
#define MARGIN 1e-4f    // flag threshold on scaled scores (f32 err ~4e-6 worst case)

// ---------------- workspace layout (bytes) ----------------
#define OFF_QT    ((size_t)0)            // f32 [32][64][1024]   8 MiB
#define OFF_KT    ((size_t)8388608)      // f32 [32][64][1024]   8 MiB
#define OFF_H     ((size_t)16777216)     // f32 [32][1024][128] 16 MiB
#define OFF_DEG   ((size_t)33554432)     // i32 [32][1024]      128 KiB
#define OFF_BMP   ((size_t)33685504)     // u32 [32][1024][32]    4 MiB
#define OFF_FLAG  ((size_t)37879808)     // i32 [32][1024]      128 KiB
#define OFF_TOPK  ((size_t)38010880)     // i32 [32][1024][16]    2 MiB
#define OFF_W64   ((size_t)40108032)     // f64 Wq64[8192], Wk64[8192]  128 KiB
#define OFF_QT64  ((size_t)40239104)     // f64 [32][64][1024]  16 MiB
#define OFF_KT64  ((size_t)57016320)     // f64 [32][64][1024]  16 MiB
#define OFF_TMP   ((size_t)0)            // f32 [32][1024][128] 16 MiB (overlaps QT/KT, dead by then)
// total 73,793,536 B (~70.4 MiB)

__global__ __launch_bounds__(256) void k_zero(uint4* __restrict__ p, int n4) {
    int i = blockIdx.x * 256 + threadIdx.x;
    if (i < n4) p[i] = make_uint4(0u, 0u, 0u, 0u);
}

__global__ __launch_bounds__(256) void k_upcast(const float* __restrict__ Wq,
                                                const float* __restrict__ Wk,
                                                double* __restrict__ Wq64,
                                                double* __restrict__ Wk64) {
    int i = blockIdx.x * 256 + threadIdx.x;  // 0..8191
    Wq64[i] = (double)Wq[i];
    Wk64[i] = (double)Wk[i];
}

// q,k in f64 (exact vs numpy-f64 ref up to ~1e-15), also rounded-to-f32 copies for the fast path.
// grid (16 ntiles, 32 b), block 256. lane = node within 64-node tile.
__global__ __launch_bounds__(256) void k_qk(
    const float* __restrict__ x, const float* __restrict__ bq, const float* __restrict__ bk,
    const double* __restrict__ Wq64, const double* __restrict__ Wk64,
    float* __restrict__ qT, float* __restrict__ kT,
    double* __restrict__ qT64, double* __restrict__ kT64)
{
    __shared__ float xs[64 * 129];   // xs[node][f], pad 129 -> conflict-free lane-strided access
    const int t = threadIdx.x;
    const int l = t & 63;
    const int w = t >> 6;
    const int uw = __builtin_amdgcn_readfirstlane(w);
    const int n0 = blockIdx.x * 64;
    const int b  = blockIdx.y;

    {   // load x tile: xs[j][f] = x[b][f][n0+j]  (coalesced over j)
        const int j = t & 63, fg = t >> 6;
        for (int ff = 0; ff < 32; ++ff) {
            int f = fg + ff * 4;
            xs[j * 129 + f] = x[((size_t)b * NF + f) * NN + n0 + j];
        }
    }
    __syncthreads();

    double accq[16], acck[16];
    #pragma unroll
    for (int dd = 0; dd < 16; ++dd) {
        int d = uw * 16 + dd;
        accq[dd] = (double)bq[d];
        acck[dd] = (double)bk[d];
    }
    for (int fc = 0; fc < 32; ++fc) {
        double dx0 = (double)xs[l * 129 + fc * 4 + 0];
        double dx1 = (double)xs[l * 129 + fc * 4 + 1];
        double dx2 = (double)xs[l * 129 + fc * 4 + 2];
        double dx3 = (double)xs[l * 129 + fc * 4 + 3];
        #pragma unroll
        for (int dd = 0; dd < 16; ++dd) {
            int d = uw * 16 + dd;   // uniform -> scalar loads of weights
            const double* wq = &Wq64[d * NF + fc * 4];
            const double* wk = &Wk64[d * NF + fc * 4];
            accq[dd] += dx0 * wq[0] + dx1 * wq[1] + dx2 * wq[2] + dx3 * wq[3];
            acck[dd] += dx0 * wk[0] + dx1 * wk[1] + dx2 * wk[2] + dx3 * wk[3];
        }
    }
    #pragma unroll
    for (int dd = 0; dd < 16; ++dd) {
        int d = uw * 16 + dd;
        size_t idx = ((size_t)b * NDG + d) * NN + n0 + l;   // coalesced over lane
        qT[idx]   = (float)accq[dd];
        kT[idx]   = (float)acck[dd];
        qT64[idx] = accq[dd];
        kT64[idx] = acck[dd];
    }
}

// h = nf @ Wg.T  (f32). grid (16,32), block 256, lane = node.
__global__ __launch_bounds__(256) void k_h(
    const float* __restrict__ x, const float* __restrict__ Wg, float* __restrict__ h)
{
    __shared__ float xs[64 * 129];
    const int t = threadIdx.x;
    const int l = t & 63;
    const int w = t >> 6;
    const int uw = __builtin_amdgcn_readfirstlane(w);
    const int n0 = blockIdx.x * 64;
    const int b  = blockIdx.y;

    {
        const int j = t & 63, fg = t >> 6;
        for (int ff = 0; ff < 32; ++ff) {
            int f = fg + ff * 4;
            xs[j * 129 + f] = x[((size_t)b * NF + f) * NN + n0 + j];
        }
    }
    __syncthreads();

    float acc[32];
    #pragma unroll
    for (int i = 0; i < 32; ++i) acc[i] = 0.f;
    for (int fc = 0; fc < 32; ++fc) {
        float x0 = xs[l * 129 + fc * 4 + 0];
        float x1 = xs[l * 129 + fc * 4 + 1];
        float x2 = xs[l * 129 + fc * 4 + 2];
        float x3 = xs[l * 129 + fc * 4 + 3];
        #pragma unroll
        for (int ff = 0; ff < 32; ++ff) {
            int fp = uw * 32 + ff;    // uniform -> scalar weight loads
            const float* wg = &Wg[fp * NF + fc * 4];
            acc[ff] += x0 * wg[0] + x1 * wg[1] + x2 * wg[2] + x3 * wg[3];
        }
    }
    __syncthreads();   // everyone done reading x
    #pragma unroll
    for (int ff = 0; ff < 32; ++ff) xs[l * 129 + uw * 32 + ff] = acc[ff];  // hs[node][f']
    __syncthreads();
    for (int r = 0; r < 32; ++r) {
        int idx = t + 256 * r;            // 0..8191
        int n = idx >> 7, f = idx & 127;
        h[((size_t)b * NN + n0 + n) * NF + f] = xs[n * 129 + f];  // coalesced
    }
}

// scores + top-15 (f32) + deg/bitmap atomics + gap flag. grid (64,32), block 256.
// wave w handles rows row0..row0+3; lane owns cols lane*4+g per 256-col tile.
__global__ __launch_bounds__(256) void k_score(
    const float* __restrict__ qT, const float* __restrict__ kT,
    int* __restrict__ deg, unsigned int* __restrict__ bmp,
    int* __restrict__ topk, int* __restrict__ flag)
{
    __shared__ float  ks[32 * 256];     // 32 KiB k-tile [d][c]
    __shared__ float4 qpack[4 * 64];    // per-wave q rows packed by d
    const int t = threadIdx.x;
    const int l = t & 63;
    const int w = t >> 6;
    const int b = blockIdx.y;
    const int row0 = blockIdx.x * 16 + w * 4;

    {   // qpack[w][d] = {q[row0..row0+3][d]}; lane = d
        float q0 = qT[((size_t)b * NDG + l) * NN + row0 + 0];
        float q1 = qT[((size_t)b * NDG + l) * NN + row0 + 1];
        float q2 = qT[((size_t)b * NDG + l) * NN + row0 + 2];
        float q3 = qT[((size_t)b * NDG + l) * NN + row0 + 3];
        qpack[w * 64 + l] = make_float4(q0, q1, q2, q3);
    }

    float sc[4][16];
    #pragma unroll
    for (int r = 0; r < 4; ++r)
        #pragma unroll
        for (int j = 0; j < 16; ++j) sc[r][j] = 0.f;

    #pragma unroll
    for (int tt = 0; tt < 4; ++tt) {        // 256-col tiles
        #pragma unroll
        for (int hh = 0; hh < 2; ++hh) {    // 32-d halves
            __syncthreads();
            #pragma unroll
            for (int i = 0; i < 8; ++i) {   // stage k tile
                int flat = (t + 256 * i) * 4;
                int d = flat >> 8, c = flat & 255;
                *(float4*)&ks[flat] =
                    *(const float4*)&kT[((size_t)b * NDG + hh * 32 + d) * NN + tt * 256 + c];
            }
            __syncthreads();
            #pragma unroll 8
            for (int d = 0; d < 32; ++d) {
                float4 kv = *(float4*)&ks[d * 256 + l * 4];        // lane-consecutive 16B
                float4 qv = qpack[w * 64 + hh * 32 + d];           // broadcast
                sc[0][tt*4+0] += qv.x*kv.x; sc[0][tt*4+1] += qv.x*kv.y; sc[0][tt*4+2] += qv.x*kv.z; sc[0][tt*4+3] += qv.x*kv.w;
                sc[1][tt*4+0] += qv.y*kv.x; sc[1][tt*4+1] += qv.y*kv.y; sc[1][tt*4+2] += qv.y*kv.z; sc[1][tt*4+3] += qv.y*kv.w;
                sc[2][tt*4+0] += qv.z*kv.x; sc[2][tt*4+1] += qv.z*kv.y; sc[2][tt*4+2] += qv.z*kv.z; sc[2][tt*4+3] += qv.z*kv.w;
                sc[3][tt*4+0] += qv.w*kv.x; sc[3][tt*4+1] += qv.w*kv.y; sc[3][tt*4+2] += qv.w*kv.z; sc[3][tt*4+3] += qv.w*kv.w;
            }
        }
    }

    // scale 1/sqrt(64) + diagonal mask
    #pragma unroll
    for (int r = 0; r < 4; ++r) {
        int row = row0 + r;
        #pragma unroll
        for (int j = 0; j < 16; ++j) {
            int col = ((j >> 2) << 8) + (l << 2) + (j & 3);
            float v = sc[r][j] * 0.125f;
            sc[r][j] = (col == row) ? -__builtin_inff() : v;
        }
    }

    // top-15 per row: 15 argmax passes + one extra for the 15/16 gap
    #pragma unroll
    for (int r = 0; r < 4; ++r) {
        int row = row0 + r;
        float v15 = 0.f;
        for (int it = 0; it < 16; ++it) {
            float lv = -__builtin_inff();
            int   lc = 0x7fffffff;
            #pragma unroll
            for (int j = 0; j < 16; ++j) {
                int col = ((j >> 2) << 8) + (l << 2) + (j & 3);
                if (sc[r][j] > lv) { lv = sc[r][j]; lc = col; }   // strict > : lowest col on tie
            }
            #pragma unroll
            for (int off = 1; off < 64; off <<= 1) {
                float ov = __shfl_xor(lv, off, 64);
                int   oc = __shfl_xor(lc, off, 64);
                if (ov > lv || (ov == lv && oc < lc)) { lv = ov; lc = oc; }
            }
            if (it < 15) {
                #pragma unroll
                for (int j = 0; j < 16; ++j) {
                    int col = ((j >> 2) << 8) + (l << 2) + (j & 3);
                    if (col == lc) sc[r][j] = -__builtin_inff();
                }
                if (l == 0) {
                    atomicAdd(&deg[b * NN + lc], 1);
                    atomicOr(&bmp[((size_t)b * NN + lc) * 32 + (row >> 5)], 1u << (row & 31));
                    topk[(b * NN + row) * 16 + it] = lc;
                }
                if (it == 14) v15 = lv;
            } else if (l == 0) {
                flag[b * NN + row] = ((v15 - lv) < MARGIN) ? 1 : 0;
            }
        }
    }
}

// exact f64 re-selection for flagged rows; patches deg/bitmap by set-diff.
// grid (32,32), block 64 (one wave); each block sweeps 32 rows.
__global__ __launch_bounds__(64) void k_repair(
    const double* __restrict__ qT64, const double* __restrict__ kT64,
    const int* __restrict__ topk, const int* __restrict__ flag,
    int* __restrict__ deg, unsigned int* __restrict__ bmp)
{
    const int b = blockIdx.y;
    const int l = threadIdx.x;
    __shared__ double qld[64];
    __shared__ int oldset[15], newset[15];
    const double NEGINF = -__builtin_inf();

    for (int rr = 0; rr < 32; ++rr) {
        const int row = blockIdx.x * 32 + rr;
        if (!flag[b * NN + row]) continue;

        qld[l] = qT64[((size_t)b * NDG + l) * NN + row];
        if (l < 15) oldset[l] = topk[(b * NN + row) * 16 + l];
        __syncthreads();

        double sc[16];
        #pragma unroll
        for (int tt = 0; tt < 16; ++tt) sc[tt] = 0.0;
        for (int d = 0; d < 64; ++d) {
            double qd = qld[d];
            const double* kr = &kT64[((size_t)b * NDG + d) * NN];
            #pragma unroll
            for (int tt = 0; tt < 16; ++tt) sc[tt] += qd * kr[l + 64 * tt];  // coalesced
        }
        #pragma unroll
        for (int tt = 0; tt < 16; ++tt) if (l + 64 * tt == row) sc[tt] = NEGINF;

        for (int it = 0; it < 15; ++it) {
            double lv = NEGINF; int lc = 0x7fffffff;
            #pragma unroll
            for (int tt = 0; tt < 16; ++tt)
                if (sc[tt] > lv) { lv = sc[tt]; lc = l + 64 * tt; }
            #pragma unroll
            for (int off = 1; off < 64; off <<= 1) {
                double ov = __shfl_xor(lv, off, 64);
                int    oc = __shfl_xor(lc, off, 64);
                if (ov > lv || (ov == lv && oc < lc)) { lv = ov; lc = oc; }
            }
            #pragma unroll
            for (int tt = 0; tt < 16; ++tt) if (l + 64 * tt == lc) sc[tt] = NEGINF;
            if (l == 0) newset[it] = lc;
        }
        __syncthreads();
        if (l < 15) {
            int cn = newset[l];
            bool found = false;
            #pragma unroll
            for (int j = 0; j < 15; ++j) found = found || (oldset[j] == cn);
            if (!found) {
                atomicAdd(&deg[b * NN + cn], 1);
                atomicOr(&bmp[((size_t)b * NN + cn) * 32 + (row >> 5)], 1u << (row & 31));
            }
            int co = oldset[l];
            found = false;
            #pragma unroll
            for (int j = 0; j < 15; ++j) found = found || (newset[j] == co);
            if (!found) {
                atomicSub(&deg[b * NN + co], 1);
                atomicAnd(&bmp[((size_t)b * NN + co) * 32 + (row >> 5)], ~(1u << (row & 31)));
            }
        }
        __syncthreads();
    }
}

// gather per target node via bitmap scan (deterministic order). grid (1024,32), block 128.
__global__ __launch_bounds__(128) void k_gather(
    const float* __restrict__ h, const float* __restrict__ bg,
    const int* __restrict__ deg, const unsigned int* __restrict__ bmp,
    float* __restrict__ tmp)
{
    const int tgt = blockIdx.x, b = blockIdx.y, f = threadIdx.x;
    const float dt = 1.0f / sqrtf((float)(deg[b * NN + tgt] + 2));
    float acc = bg[f] + 2.f * dt * dt * h[((size_t)b * NN + tgt) * NF + f];
    const unsigned int* brow = &bmp[((size_t)b * NN + tgt) * 32];
    for (int wd = 0; wd < 32; ++wd) {
        unsigned int word = brow[wd];
        while (word) {
            int s = __builtin_ctz(word);
            word &= word - 1;
            int src = wd * 32 + s;
            float ds = 1.0f / sqrtf((float)(deg[b * NN + src] + 2));
            acc += h[((size_t)b * NN + src) * NF + f] * (ds * dt);
        }
    }
    tmp[((size_t)b * NN + tgt) * NF + f] = acc;
}

// [b][n][f] -> [b][f][n]. grid (32, 4, 32), block 256.
__global__ __launch_bounds__(256) void k_transpose(const float* __restrict__ tmp,
                                                   float* __restrict__ out)
{
    __shared__ float tile[32][33];
    const int t = threadIdx.x;
    const int n0 = blockIdx.x * 32, f0 = blockIdx.y * 32, b = blockIdx.z;
    const int c = t & 31, rb = t >> 5;
    #pragma unroll
    for (int i = 0; i < 4; ++i) {
        int r = rb + i * 8;
        tile[r][c] = tmp[((size_t)b * NN + n0 + r) * NF + f0 + c];
    }
    __syncthreads();
    #pragma unroll
    for (int i = 0; i < 4; ++i) {
        int r = rb + i * 8;
        out[((size_t)b * NF + f0 + r) * NN + n0 + c] = tile[c][r];
    }
}

extern "C" void kernel_launch(void* const* d_in, const int* in_sizes, int n_in,
                              void* d_out, int out_size, void* d_ws, size_t ws_size,
                              hipStream_t stream)
{
    const float* x  = (const float*)d_in[0];
    const float* Wq = (const float*)d_in[1];
    const float* bq = (const float*)d_in[2];
    const float* Wk = (const float*)d_in[3];
    const float* bk = (const float*)d_in[4];
    const float* Wg = (const float*)d_in[5];
    const float* bg = (const float*)d_in[6];
    float* out = (float*)d_out;
    char* ws = (char*)d_ws;

    float*        qT   = (float*)(ws + OFF_QT);
    float*        kT   = (float*)(ws + OFF_KT);
    float*        h    = (float*)(ws + OFF_H);
    int*          deg  = (int*)(ws + OFF_DEG);
    unsigned int* bmp  = (unsigned int*)(ws + OFF_BMP);
    int*          flag = (int*)(ws + OFF_FLAG);
    int*          topk = (int*)(ws + OFF_TOPK);
    double*       Wq64 = (double*)(ws + OFF_W64);
    double*       Wk64 = Wq64 + 8192;
    double*       qT64 = (double*)(ws + OFF_QT64);
    double*       kT64 = (double*)(ws + OFF_KT64);
    float*        tmp  = (float*)(ws + OFF_TMP);   // overlaps qT/kT (dead after k_score/k_repair? q/k f32 dead after k_score)

    // zero deg + bitmap (contiguous): (131072 + 4194304)/16 = 270336 uint4
    k_zero<<<1056, 256, 0, stream>>>((uint4*)(ws + OFF_DEG), 270336);
    k_upcast<<<32, 256, 0, stream>>>(Wq, Wk, Wq64, Wk64);
    k_qk<<<dim3(16, 32), 256, 0, stream>>>(x, bq, bk, Wq64, Wk64, qT, kT, qT64, kT64);
    k_h<<<dim3(16, 32), 256, 0, stream>>>(x, Wg, h);
    k_score<<<dim3(64, 32), 256, 0, stream>>>(qT, kT, deg, bmp, topk, flag);
    k_repair<<<dim3(32, 32), 64, 0, stream>>>(qT64, kT64, topk, flag, deg, bmp);
    k_gather<<<dim3(1024, 32), 128, 0, stream>>>(h, bg, deg, bmp, tmp);
    k_transpose<<<dim3(32, 4, 32), 256, 0, stream>>>(tmp, out);
}

// Round 3
// 503.016 us; speedup vs baseline: 1.3898x; 1.3898x over previous
//
#include <hip/hip_runtime.h>

#define NBATCH 32
#define NN     1024     // d_model = number of nodes
#define NF     128      // win_size = node feature dim
#define NDG    64       // graph embed dim
#define TOPK   15

// ---------------- workspace layout (bytes), total 73,793,536 (same as R1) ----------------
#define OFF_QH    ((size_t)0)            // bf16-hi q [32][1024][64]  4 MiB
#define OFF_QL    ((size_t)4194304)      // bf16-lo q                 4 MiB
#define OFF_KH    ((size_t)8388608)      // bf16-hi k                 4 MiB
#define OFF_KL    ((size_t)12582912)     // bf16-lo k                 4 MiB
#define OFF_H     ((size_t)16777216)     // f32 [32][1024][128]      16 MiB (scaled in-place -> hs)
#define OFF_DEG   ((size_t)33554432)     // i32 [32][1024]          128 KiB
#define OFF_BMP   ((size_t)33685504)     // u32 [32][1024][32]        4 MiB
#define OFF_FLAG  ((size_t)37879808)     // i32 [32][1024]          128 KiB
#define OFF_TOPK  ((size_t)38010880)     // i32 [32][1024][16]        2 MiB
#define OFF_W64   ((size_t)40108032)     // f64 Wq64[8192], Wk64[8192] 128 KiB
#define OFF_QT64  ((size_t)40239104)     // f64 [32][64][1024]       16 MiB
#define OFF_KT64  ((size_t)57016320)     // f64 [32][64][1024]       16 MiB
#define OFF_TMP   ((size_t)0)            // f32 [32][1024][128]      16 MiB (overlaps QH..KL, dead by then)

typedef short s8v  __attribute__((ext_vector_type(8)));   // 8 bf16 (4 VGPRs) MFMA operand
typedef float f4v  __attribute__((ext_vector_type(4)));   // MFMA accumulator
typedef unsigned short us8v __attribute__((ext_vector_type(8)));

__device__ inline unsigned short bf16_rne(float f) {
    unsigned u = __float_as_uint(f);
    return (unsigned short)((u + 0x7FFFu + ((u >> 16) & 1u)) >> 16);
}
__device__ inline float bf16_tof(unsigned short h) { return __uint_as_float(((unsigned)h) << 16); }

// monotone 22-bit code for f32 score in window [-4, 4): sign + 5-bit biased exp (e-113) + 16-bit mantissa
__device__ inline unsigned pack22(float s) {
    unsigned u   = __float_as_uint(s);
    int      mag = (int)(u & 0x7FFFFFFFu);
    int      t   = mag - 0x38800000;                 // bias at 2^-14
    t = t < 0 ? 0 : (t > 0x07FFFFFF ? 0x07FFFFFF : t);
    unsigned ts = (unsigned)t >> 6;                  // 21 bits
    return ((int)u < 0) ? (0x1FFFFFu - ts) : (0x200000u | ts);
}
__device__ inline float dec22(unsigned val22) {
    bool pos = (val22 & 0x200000u) != 0;
    unsigned ts = pos ? (val22 & 0x1FFFFFu) : (0x1FFFFFu - (val22 & 0x1FFFFFu));
    float f = __uint_as_float((ts << 6) + 0x38800000u);
    return pos ? f : -f;
}

__global__ __launch_bounds__(256) void k_zero(uint4* __restrict__ p, int n4) {
    int i = blockIdx.x * 256 + threadIdx.x;
    if (i < n4) p[i] = make_uint4(0u, 0u, 0u, 0u);
}

__global__ __launch_bounds__(256) void k_upcast(const float* __restrict__ Wq,
                                                const float* __restrict__ Wk,
                                                double* __restrict__ Wq64,
                                                double* __restrict__ Wk64) {
    int i = blockIdx.x * 256 + threadIdx.x;  // 0..8191
    Wq64[i] = (double)Wq[i];
    Wk64[i] = (double)Wk[i];
}

// q,k in f64 (exact repair path) + bf16 hi/lo splits in [b][n][d] layout (MFMA operand order).
// grid (16, 32), block 256. lane = node within 64-node tile.
__global__ __launch_bounds__(256) void k_qk(
    const float* __restrict__ x, const float* __restrict__ bq, const float* __restrict__ bk,
    const double* __restrict__ Wq64, const double* __restrict__ Wk64,
    unsigned short* __restrict__ qh, unsigned short* __restrict__ ql,
    unsigned short* __restrict__ kh, unsigned short* __restrict__ kl,
    double* __restrict__ qT64, double* __restrict__ kT64)
{
    __shared__ float xs[64 * 129];
    const int t = threadIdx.x;
    const int l = t & 63;
    const int w = t >> 6;
    const int uw = __builtin_amdgcn_readfirstlane(w);
    const int n0 = blockIdx.x * 64;
    const int b  = blockIdx.y;

    {   // xs[node][f] = x[b][f][n0+node]  (coalesced over node)
        const int j = t & 63, fg = t >> 6;
        for (int ff = 0; ff < 32; ++ff) {
            int f = fg + ff * 4;
            xs[j * 129 + f] = x[((size_t)b * NF + f) * NN + n0 + j];
        }
    }
    __syncthreads();

    double accq[16], acck[16];
    #pragma unroll
    for (int dd = 0; dd < 16; ++dd) {
        int d = uw * 16 + dd;
        accq[dd] = (double)bq[d];
        acck[dd] = (double)bk[d];
    }
    for (int fc = 0; fc < 32; ++fc) {
        double dx0 = (double)xs[l * 129 + fc * 4 + 0];
        double dx1 = (double)xs[l * 129 + fc * 4 + 1];
        double dx2 = (double)xs[l * 129 + fc * 4 + 2];
        double dx3 = (double)xs[l * 129 + fc * 4 + 3];
        #pragma unroll
        for (int dd = 0; dd < 16; ++dd) {
            int d = uw * 16 + dd;   // uniform -> scalar loads of weights
            const double* wq = &Wq64[d * NF + fc * 4];
            const double* wk = &Wk64[d * NF + fc * 4];
            accq[dd] += dx0 * wq[0] + dx1 * wq[1] + dx2 * wq[2] + dx3 * wq[3];
            acck[dd] += dx0 * wk[0] + dx1 * wk[1] + dx2 * wk[2] + dx3 * wk[3];
        }
    }
    // f64 [d][n] for repair (coalesced over lane)
    #pragma unroll
    for (int dd = 0; dd < 16; ++dd) {
        int d = uw * 16 + dd;
        size_t idx = ((size_t)b * NDG + d) * NN + n0 + l;
        qT64[idx] = accq[dd];
        kT64[idx] = acck[dd];
    }
    // bf16 hi/lo splits, [n][d] layout
    us8v qh0, qh1, ql0, ql1, kh0, kh1, kl0, kl1;
    #pragma unroll
    for (int dd = 0; dd < 16; ++dd) {
        float fq = (float)accq[dd];
        unsigned short h1 = bf16_rne(fq);
        unsigned short l1 = bf16_rne(fq - bf16_tof(h1));
        float fk = (float)acck[dd];
        unsigned short h2 = bf16_rne(fk);
        unsigned short l2 = bf16_rne(fk - bf16_tof(h2));
        if (dd < 8) { qh0[dd] = h1; ql0[dd] = l1; kh0[dd] = h2; kl0[dd] = l2; }
        else        { qh1[dd-8] = h1; ql1[dd-8] = l1; kh1[dd-8] = h2; kl1[dd-8] = l2; }
    }
    size_t nb = ((size_t)b * NN + n0 + l) * NDG + uw * 16;
    *(us8v*)&qh[nb] = qh0; *(us8v*)&qh[nb + 8] = qh1;
    *(us8v*)&ql[nb] = ql0; *(us8v*)&ql[nb + 8] = ql1;
    *(us8v*)&kh[nb] = kh0; *(us8v*)&kh[nb + 8] = kh1;
    *(us8v*)&kl[nb] = kl0; *(us8v*)&kl[nb + 8] = kl1;
}

// h = nf @ Wg.T  (f32). grid (16,32), block 256, lane = node.
__global__ __launch_bounds__(256) void k_h(
    const float* __restrict__ x, const float* __restrict__ Wg, float* __restrict__ h)
{
    __shared__ float xs[64 * 129];
    const int t = threadIdx.x;
    const int l = t & 63;
    const int w = t >> 6;
    const int uw = __builtin_amdgcn_readfirstlane(w);
    const int n0 = blockIdx.x * 64;
    const int b  = blockIdx.y;

    {
        const int j = t & 63, fg = t >> 6;
        for (int ff = 0; ff < 32; ++ff) {
            int f = fg + ff * 4;
            xs[j * 129 + f] = x[((size_t)b * NF + f) * NN + n0 + j];
        }
    }
    __syncthreads();

    float acc[32];
    #pragma unroll
    for (int i = 0; i < 32; ++i) acc[i] = 0.f;
    for (int fc = 0; fc < 32; ++fc) {
        float x0 = xs[l * 129 + fc * 4 + 0];
        float x1 = xs[l * 129 + fc * 4 + 1];
        float x2 = xs[l * 129 + fc * 4 + 2];
        float x3 = xs[l * 129 + fc * 4 + 3];
        #pragma unroll
        for (int ff = 0; ff < 32; ++ff) {
            int fp = uw * 32 + ff;
            const float* wg = &Wg[fp * NF + fc * 4];
            acc[ff] += x0 * wg[0] + x1 * wg[1] + x2 * wg[2] + x3 * wg[3];
        }
    }
    __syncthreads();
    #pragma unroll
    for (int ff = 0; ff < 32; ++ff) xs[l * 129 + uw * 32 + ff] = acc[ff];
    __syncthreads();
    for (int r = 0; r < 32; ++r) {
        int idx = t + 256 * r;
        int n = idx >> 7, f = idx & 127;
        h[((size_t)b * NN + n0 + n) * NF + f] = xs[n * 129 + f];
    }
}

#define CE(x,y) { unsigned a_ = v[x], b_ = v[y]; v[x] = a_ > b_ ? a_ : b_; v[y] = a_ > b_ ? b_ : a_; }

// MFMA bf16-split scores + packed top-15 + deg/bitmap atomics + gap flag.
// grid (64, 32): block = 16 rows; wave w computes cols [256w,256w+256); selection wave w -> rows 4w..4w+3.
__global__ __launch_bounds__(256) void k_score(
    const unsigned short* __restrict__ qh, const unsigned short* __restrict__ ql,
    const unsigned short* __restrict__ kh, const unsigned short* __restrict__ kl,
    int* __restrict__ deg, unsigned int* __restrict__ bmp,
    int* __restrict__ topk, int* __restrict__ flag)
{
    __shared__ unsigned pk[16 * 1024];    // packed scores, 64 KiB
    const int t = threadIdx.x, l = t & 63, w = t >> 6;
    const int b = blockIdx.y, row0 = blockIdx.x * 16;
    const int m = l & 15, q4 = l >> 4;

    // A fragments: q rows (hi/lo, two K-halves). A[m][k]: m=lane&15, k=(lane>>4)*8+j
    size_t abase = ((size_t)b * NN + row0 + m) * NDG + q4 * 8;
    s8v ah0 = *(const s8v*)&qh[abase];
    s8v ah1 = *(const s8v*)&qh[abase + 32];
    s8v al0 = *(const s8v*)&ql[abase];
    s8v al1 = *(const s8v*)&ql[abase + 32];

    const int colbase = w * 256;
    #pragma unroll 4
    for (int tt = 0; tt < 16; ++tt) {
        int col = colbase + tt * 16 + m;
        size_t bbase = ((size_t)b * NN + col) * NDG + q4 * 8;
        s8v bh0 = *(const s8v*)&kh[bbase];
        s8v bh1 = *(const s8v*)&kh[bbase + 32];
        s8v bl0 = *(const s8v*)&kl[bbase];
        s8v bl1 = *(const s8v*)&kl[bbase + 32];
        f4v acc = {0.f, 0.f, 0.f, 0.f};
        acc = __builtin_amdgcn_mfma_f32_16x16x32_bf16(al0, bl0, acc, 0, 0, 0);
        acc = __builtin_amdgcn_mfma_f32_16x16x32_bf16(al1, bl1, acc, 0, 0, 0);
        acc = __builtin_amdgcn_mfma_f32_16x16x32_bf16(ah0, bl0, acc, 0, 0, 0);
        acc = __builtin_amdgcn_mfma_f32_16x16x32_bf16(ah1, bl1, acc, 0, 0, 0);
        acc = __builtin_amdgcn_mfma_f32_16x16x32_bf16(al0, bh0, acc, 0, 0, 0);
        acc = __builtin_amdgcn_mfma_f32_16x16x32_bf16(al1, bh1, acc, 0, 0, 0);
        acc = __builtin_amdgcn_mfma_f32_16x16x32_bf16(ah0, bh0, acc, 0, 0, 0);
        acc = __builtin_amdgcn_mfma_f32_16x16x32_bf16(ah1, bh1, acc, 0, 0, 0);
        // C/D: col=lane&15 (this tile's col), row=(lane>>4)*4+reg. Pack + LDS write (XOR-swizzled pos).
        #pragma unroll
        for (int r = 0; r < 4; ++r) {
            int row  = q4 * 4 + r;           // local 0..15
            int grow = row0 + row;
            float s = acc[r] * 0.125f;
            unsigned p = (col == grow) ? 0u : ((pack22(s) << 10) | (unsigned)(1023 - col));
            int pos = col ^ (((row >> 2) & 1) << 4);   // 2-way (free) banks on write & read
            pk[row * 1024 + pos] = p;
        }
    }
    __syncthreads();

    for (int rr = 0; rr < 4; ++rr) {
        const int row = w * 4 + rr, grow = row0 + row;
        unsigned v[16];
        #pragma unroll
        for (int j = 0; j < 16; ++j) v[j] = pk[row * 1024 + l + 64 * j];
        // Batcher odd-even mergesort 16, descending (63 CE)
        CE(0,1) CE(2,3) CE(4,5) CE(6,7) CE(8,9) CE(10,11) CE(12,13) CE(14,15)
        CE(0,2) CE(1,3) CE(4,6) CE(5,7) CE(8,10) CE(9,11) CE(12,14) CE(13,15)
        CE(1,2) CE(5,6) CE(9,10) CE(13,14)
        CE(0,4) CE(1,5) CE(2,6) CE(3,7) CE(8,12) CE(9,13) CE(10,14) CE(11,15)
        CE(2,4) CE(3,5) CE(10,12) CE(11,13)
        CE(1,2) CE(3,4) CE(5,6) CE(9,10) CE(11,12) CE(13,14)
        CE(0,8) CE(1,9) CE(2,10) CE(3,11) CE(4,12) CE(5,13) CE(6,14) CE(7,15)
        CE(4,8) CE(5,9) CE(6,10) CE(7,11)
        CE(2,4) CE(3,5) CE(6,8) CE(7,9) CE(10,12) CE(11,13)
        CE(1,2) CE(3,4) CE(5,6) CE(7,8) CE(9,10) CE(11,12) CE(13,14)

        unsigned p14 = 0, p15 = 0;
        for (int it = 0; it < 16; ++it) {
            unsigned mx = v[0];
            #pragma unroll
            for (int off = 1; off < 64; off <<= 1) {
                unsigned o = (unsigned)__shfl_xor((int)mx, off, 64);
                mx = mx > o ? mx : o;
            }
            bool iw = (v[0] == mx);
            #pragma unroll
            for (int i = 0; i < 15; ++i) v[i] = iw ? v[i + 1] : v[i];
            v[15] = iw ? 0u : v[15];
            if (it < 15) {
                if (l == 0) {
                    int col = 1023 - (int)(mx & 1023u);
                    atomicAdd(&deg[b * NN + col], 1);
                    atomicOr(&bmp[((size_t)b * NN + col) * 32 + (grow >> 5)], 1u << (grow & 31));
                    topk[(b * NN + grow) * 16 + it] = col;
                }
                if (it == 14) p14 = mx;
            } else {
                p15 = mx;
            }
        }
        if (l == 0) {
            float a15 = dec22(p14 >> 10), a16 = dec22(p15 >> 10);
            unsigned e15 = (__float_as_uint(fabsf(a15)) >> 23) & 255u;
            unsigned e16 = (__float_as_uint(fabsf(a16)) >> 23) & 255u;
            unsigned e = e15 > e16 ? e15 : e16;
            float qq = __uint_as_float((e - 17) << 23);    // code quantum at this magnitude
            flag[b * NN + grow] = ((a15 - a16) < (4.f * qq + 1e-4f)) ? 1 : 0;
        }
    }
}

// exact f64 re-selection for flagged rows; patches deg/bitmap by set-diff.
__global__ __launch_bounds__(64) void k_repair(
    const double* __restrict__ qT64, const double* __restrict__ kT64,
    const int* __restrict__ topk, const int* __restrict__ flag,
    int* __restrict__ deg, unsigned int* __restrict__ bmp)
{
    const int b = blockIdx.y;
    const int l = threadIdx.x;
    __shared__ double qld[64];
    __shared__ int oldset[15], newset[15];
    const double NEGINF = -__builtin_inf();

    for (int rr = 0; rr < 32; ++rr) {
        const int row = blockIdx.x * 32 + rr;
        if (!flag[b * NN + row]) continue;

        qld[l] = qT64[((size_t)b * NDG + l) * NN + row];
        if (l < 15) oldset[l] = topk[(b * NN + row) * 16 + l];
        __syncthreads();

        double sc[16];
        #pragma unroll
        for (int tt = 0; tt < 16; ++tt) sc[tt] = 0.0;
        for (int d = 0; d < 64; ++d) {
            double qd = qld[d];
            const double* kr = &kT64[((size_t)b * NDG + d) * NN];
            #pragma unroll
            for (int tt = 0; tt < 16; ++tt) sc[tt] += qd * kr[l + 64 * tt];
        }
        #pragma unroll
        for (int tt = 0; tt < 16; ++tt) if (l + 64 * tt == row) sc[tt] = NEGINF;

        for (int it = 0; it < 15; ++it) {
            double lv = NEGINF; int lc = 0x7fffffff;
            #pragma unroll
            for (int tt = 0; tt < 16; ++tt)
                if (sc[tt] > lv) { lv = sc[tt]; lc = l + 64 * tt; }
            #pragma unroll
            for (int off = 1; off < 64; off <<= 1) {
                double ov = __shfl_xor(lv, off, 64);
                int    oc = __shfl_xor(lc, off, 64);
                if (ov > lv || (ov == lv && oc < lc)) { lv = ov; lc = oc; }
            }
            #pragma unroll
            for (int tt = 0; tt < 16; ++tt) if (l + 64 * tt == lc) sc[tt] = NEGINF;
            if (l == 0) newset[it] = lc;
        }
        __syncthreads();
        if (l < 15) {
            int cn = newset[l];
            bool found = false;
            #pragma unroll
            for (int j = 0; j < 15; ++j) found = found || (oldset[j] == cn);
            if (!found) {
                atomicAdd(&deg[b * NN + cn], 1);
                atomicOr(&bmp[((size_t)b * NN + cn) * 32 + (row >> 5)], 1u << (row & 31));
            }
            int co = oldset[l];
            found = false;
            #pragma unroll
            for (int j = 0; j < 15; ++j) found = found || (newset[j] == co);
            if (!found) {
                atomicSub(&deg[b * NN + co], 1);
                atomicAnd(&bmp[((size_t)b * NN + co) * 32 + (row >> 5)], ~(1u << (row & 31)));
            }
        }
        __syncthreads();
    }
}

// hs = h * dinv(node), in place. grid 4096, block 256, float4 per thread.
__global__ __launch_bounds__(256) void k_finalize(const int* __restrict__ deg, float* __restrict__ h)
{
    int gid = blockIdx.x * 256 + threadIdx.x;      // 0 .. 1048575
    int base = gid * 4;
    int b = base >> 17, n = (base >> 7) & 1023;
    float dv = rsqrtf((float)(deg[b * NN + n] + 2));
    float4 h4 = *(float4*)&h[base];
    h4.x *= dv; h4.y *= dv; h4.z *= dv; h4.w *= dv;
    *(float4*)&h[base] = h4;
}

// gather per target via compacted LDS edge list. grid (1024,32), block 128 (f = thread).
__global__ __launch_bounds__(128) void k_gather(
    const float* __restrict__ hs, const float* __restrict__ bg,
    const int* __restrict__ deg, const unsigned int* __restrict__ bmp,
    float* __restrict__ tmp)
{
    __shared__ int list[1024];
    __shared__ int scnt;
    const int tgt = blockIdx.x, b = blockIdx.y, t = threadIdx.x;
    if (t < 32) {
        unsigned word = bmp[((size_t)b * NN + tgt) * 32 + t];
        int pc = __popc(word);
        int pre = pc;
        #pragma unroll
        for (int d = 1; d < 32; d <<= 1) {
            int o = __shfl_up(pre, d, 32);
            if (t >= d) pre += o;
        }
        if (t == 31) scnt = pre;
        int idx = pre - pc;
        while (word) {
            int s = __ffs(word) - 1;
            word &= word - 1;
            list[idx++] = t * 32 + s;
        }
    }
    __syncthreads();
    const int f = t;
    float dt = rsqrtf((float)(deg[b * NN + tgt] + 2));
    float acc = 2.0f * hs[((size_t)b * NN + tgt) * NF + f];
    const int cnt = scnt;
    for (int e = 0; e < cnt; ++e) {
        int src = list[e];
        acc += hs[((size_t)b * NN + src) * NF + f];
    }
    tmp[((size_t)b * NN + tgt) * NF + f] = bg[f] + dt * acc;
}

// [b][n][f] -> [b][f][n]. grid (32, 4, 32), block 256.
__global__ __launch_bounds__(256) void k_transpose(const float* __restrict__ tmp,
                                                   float* __restrict__ out)
{
    __shared__ float tile[32][33];
    const int t = threadIdx.x;
    const int n0 = blockIdx.x * 32, f0 = blockIdx.y * 32, b = blockIdx.z;
    const int c = t & 31, rb = t >> 5;
    #pragma unroll
    for (int i = 0; i < 4; ++i) {
        int r = rb + i * 8;
        tile[r][c] = tmp[((size_t)b * NN + n0 + r) * NF + f0 + c];
    }
    __syncthreads();
    #pragma unroll
    for (int i = 0; i < 4; ++i) {
        int r = rb + i * 8;
        out[((size_t)b * NF + f0 + r) * NN + n0 + c] = tile[c][r];
    }
}

extern "C" void kernel_launch(void* const* d_in, const int* in_sizes, int n_in,
                              void* d_out, int out_size, void* d_ws, size_t ws_size,
                              hipStream_t stream)
{
    const float* x  = (const float*)d_in[0];
    const float* Wq = (const float*)d_in[1];
    const float* bq = (const float*)d_in[2];
    const float* Wk = (const float*)d_in[3];
    const float* bk = (const float*)d_in[4];
    const float* Wg = (const float*)d_in[5];
    const float* bg = (const float*)d_in[6];
    float* out = (float*)d_out;
    char* ws = (char*)d_ws;

    unsigned short* qh = (unsigned short*)(ws + OFF_QH);
    unsigned short* ql = (unsigned short*)(ws + OFF_QL);
    unsigned short* kh = (unsigned short*)(ws + OFF_KH);
    unsigned short* kl = (unsigned short*)(ws + OFF_KL);
    float*          h   = (float*)(ws + OFF_H);
    int*            deg = (int*)(ws + OFF_DEG);
    unsigned int*   bmp = (unsigned int*)(ws + OFF_BMP);
    int*            flg = (int*)(ws + OFF_FLAG);
    int*            tpk = (int*)(ws + OFF_TOPK);
    double*         Wq64 = (double*)(ws + OFF_W64);
    double*         Wk64 = Wq64 + 8192;
    double*         qT64 = (double*)(ws + OFF_QT64);
    double*         kT64 = (double*)(ws + OFF_KT64);
    float*          tmp  = (float*)(ws + OFF_TMP);

    // zero deg + bmp (contiguous 4,325,376 B)
    k_zero<<<1056, 256, 0, stream>>>((uint4*)(ws + OFF_DEG), 270336);
    k_upcast<<<32, 256, 0, stream>>>(Wq, Wk, Wq64, Wk64);
    k_qk<<<dim3(16, 32), 256, 0, stream>>>(x, bq, bk, Wq64, Wk64, qh, ql, kh, kl, qT64, kT64);
    k_h<<<dim3(16, 32), 256, 0, stream>>>(x, Wg, h);
    k_score<<<dim3(64, 32), 256, 0, stream>>>(qh, ql, kh, kl, deg, bmp, tpk, flg);
    k_repair<<<dim3(32, 32), 64, 0, stream>>>(qT64, kT64, tpk, flg, deg, bmp);
    k_finalize<<<4096, 256, 0, stream>>>(deg, h);
    k_gather<<<dim3(1024, 32), 128, 0, stream>>>(h, bg, deg, bmp, tmp);
    k_transpose<<<dim3(32, 4, 32), 256, 0, stream>>>(tmp, out);
}